// Round 5
// baseline (222.555 us; speedup 1.0000x reference)
//
#include <hip/hip_runtime.h>

// RoPE: X (L=2048, D=4096, N=4) fp32 -> out same shape.
// R4: passed, absmax 0.03125 (thr 0.110625). Rope kernel < 79us (absent from
// top-5; fills are 80us each); bench dur 218.65 includes ~160us harness fills.
// R5 change: (1) theta via 2048-entry table (setup kernel, same double pow ->
// bit-identical); (2) sincosf (Payne-Hanek slow path at ang~2e7) replaced by
// double-precision reduction to revolutions + HW v_sin_f32/v_cos_f32.
// ang = fl32(pos * theta) kept as a single f32 multiply (matches numpy's
// rounding; ulp(ang) ~ 2 rad, the rounding IS the value).

#define L_DIM 2048
#define D_DIM 4096
#define HALF 2048

__global__ __launch_bounds__(256) void theta_kernel(float* __restrict__ theta_tab) {
    int j = blockIdx.x * blockDim.x + threadIdx.x;   // 0..2047
    // Correctly-rounded f32 of 10000^(j/2048) via double pow (matches numpy
    // float32 np.power to ~0-1 ulp). (double)j * (1.0/2048.0) is exact.
    theta_tab[j] = (float)pow(10000.0, (double)j * (1.0 / 2048.0));
}

__global__ __launch_bounds__(256) void rope_kernel(const float4* __restrict__ X,
                                                   const float* __restrict__ theta_tab,
                                                   float4* __restrict__ out) {
    int idx = blockIdx.x * blockDim.x + threadIdx.x;   // 0 .. L*HALF-1
    int l = idx >> 11;          // idx / HALF
    int j = idx & (HALF - 1);   // idx % HALF

    float theta = theta_tab[j];            // 8 KB table, L1/L2-resident
    float pos = (float)(l + 1);
    float ang = pos * theta;               // single f32 multiply (numpy chain)

    // Accurate reduction in double: (double)ang is exact; t <= 3.34e6 so
    // frac error ~1e-9 revolutions. HW sin/cos take revolutions.
    const double INV_TWO_PI = 0.159154943091895335768883763372514362;
    double t = (double)ang * INV_TWO_PI;
    float frac = (float)(t - floor(t));    // [0,1) revolutions
    float s = __builtin_amdgcn_sinf(frac); // v_sin_f32: sin(frac * 2pi)
    float c = __builtin_amdgcn_cosf(frac); // v_cos_f32: cos(frac * 2pi)

    int base = l * D_DIM + j;              // float4 index of x1
    float4 x1 = X[base];
    float4 x2 = X[base + HALF];

    float4 o1, o2;
    o1.x = c * x1.x - s * x2.x;
    o1.y = c * x1.y - s * x2.y;
    o1.z = c * x1.z - s * x2.z;
    o1.w = c * x1.w - s * x2.w;
    o2.x = s * x1.x + c * x2.x;
    o2.y = s * x1.y + c * x2.y;
    o2.z = s * x1.z + c * x2.z;
    o2.w = s * x1.w + c * x2.w;

    out[base] = o1;
    out[base + HALF] = o2;
}

extern "C" void kernel_launch(void* const* d_in, const int* in_sizes, int n_in,
                              void* d_out, int out_size, void* d_ws, size_t ws_size,
                              hipStream_t stream) {
    const float4* X = (const float4*)d_in[0];
    float4* out = (float4*)d_out;
    float* theta_tab = (float*)d_ws;       // 8 KB scratch (re-poisoned each
                                           // call -> rebuild every launch)
    theta_kernel<<<HALF / 256, 256, 0, stream>>>(theta_tab);
    int threads = L_DIM * HALF;            // 4,194,304
    rope_kernel<<<threads / 256, 256, 0, stream>>>(X, theta_tab, out);
}